// Round 1
// baseline (157.258 us; speedup 1.0000x reference)
//
#include <hip/hip_runtime.h>
#include <math.h>

// CausalRevIN: B=16, T=8192, C=128, fp32 in/out.
// 5-pass chunked-scan decomposition (no inter-block sync):
//   P1: per-chunk sums of x and nm=1-mask
//   P2: exclusive prefix over chunks (x, nm)
//   P3: per-chunk dev^2 sums using prefix offsets
//   P4: exclusive prefix over chunks (dev^2)
//   P5: final normalize + clip
constexpr int B = 16;
constexpr int T = 8192;
constexpr int C = 128;
constexpr int LSUB = 32;           // t-rows per thread chunk
constexpr int NC = T / LSUB;       // 256 chunks along T
constexpr int CG = C / 4;          // 32 float4 channel-groups
constexpr float STD_MIN = 1e-5f;
constexpr float MAX_VAL = 100.0f;

// thread decomposition shared by P1/P3/P5:
//   gtid -> (b, k, cg); thread owns 4 channels (one float4 column) for LSUB rows.
__device__ inline void decomp(int gtid, int& b, int& k, int& cg) {
    cg = gtid & (CG - 1);
    k  = (gtid / CG) & (NC - 1);
    b  = gtid / (CG * NC);
}

__global__ __launch_bounds__(256) void k_chunk_sums(
    const float* __restrict__ x, const float* __restrict__ mask,
    float4* __restrict__ sumx, float4* __restrict__ sumnm)
{
    int gtid = blockIdx.x * 256 + threadIdx.x;
    int b, k, cg; decomp(gtid, b, k, cg);
    size_t base = ((size_t)b * T + (size_t)k * LSUB) * C;
    const float4* xp = reinterpret_cast<const float4*>(x + base) + cg;
    const float4* mp = reinterpret_cast<const float4*>(mask + base) + cg;
    float sx[4] = {0,0,0,0}, sn[4] = {0,0,0,0};
    #pragma unroll 8
    for (int t = 0; t < LSUB; ++t) {
        float4 xv = xp[(size_t)t * CG];
        float4 mv = mp[(size_t)t * CG];
        const float* xe = (const float*)&xv;
        const float* me = (const float*)&mv;
        #pragma unroll
        for (int j = 0; j < 4; ++j) {
            sx[j] += xe[j];
            sn[j] += 1.0f - me[j];
        }
    }
    size_t o = ((size_t)b * NC + k) * CG + cg;
    sumx[o]  = make_float4(sx[0], sx[1], sx[2], sx[3]);
    sumnm[o] = make_float4(sn[0], sn[1], sn[2], sn[3]);
}

// exclusive prefix over the NC chunk dimension, in place, for two arrays
__global__ __launch_bounds__(256) void k_prefix_two(float4* a0, float4* a1)
{
    int gtid = blockIdx.x * 256 + threadIdx.x;    // B*CG = 512 threads
    if (gtid >= B * CG) return;
    int cg = gtid & (CG - 1);
    int b  = gtid / CG;
    float r0[4] = {0,0,0,0}, r1[4] = {0,0,0,0};
    for (int k = 0; k < NC; ++k) {
        size_t o = ((size_t)b * NC + k) * CG + cg;
        float4 v0 = a0[o];
        float4 v1 = a1[o];
        a0[o] = make_float4(r0[0], r0[1], r0[2], r0[3]);
        a1[o] = make_float4(r1[0], r1[1], r1[2], r1[3]);
        const float* e0 = (const float*)&v0;
        const float* e1 = (const float*)&v1;
        #pragma unroll
        for (int j = 0; j < 4; ++j) { r0[j] += e0[j]; r1[j] += e1[j]; }
    }
}

__global__ __launch_bounds__(256) void k_prefix_one(float4* a0)
{
    int gtid = blockIdx.x * 256 + threadIdx.x;
    if (gtid >= B * CG) return;
    int cg = gtid & (CG - 1);
    int b  = gtid / CG;
    float r0[4] = {0,0,0,0};
    for (int k = 0; k < NC; ++k) {
        size_t o = ((size_t)b * NC + k) * CG + cg;
        float4 v0 = a0[o];
        a0[o] = make_float4(r0[0], r0[1], r0[2], r0[3]);
        const float* e0 = (const float*)&v0;
        #pragma unroll
        for (int j = 0; j < 4; ++j) r0[j] += e0[j];
    }
}

__global__ __launch_bounds__(256) void k_dev2_sums(
    const float* __restrict__ x, const float* __restrict__ mask,
    const float4* __restrict__ psumx, const float4* __restrict__ psumnm,
    float4* __restrict__ sumd2)
{
    int gtid = blockIdx.x * 256 + threadIdx.x;
    int b, k, cg; decomp(gtid, b, k, cg);
    size_t base = ((size_t)b * T + (size_t)k * LSUB) * C;
    const float4* xp = reinterpret_cast<const float4*>(x + base) + cg;
    const float4* mp = reinterpret_cast<const float4*>(mask + base) + cg;
    size_t o = ((size_t)b * NC + k) * CG + cg;
    float4 pxv = psumx[o];
    float4 pnv = psumnm[o];
    const float* px = (const float*)&pxv;
    const float* pn = (const float*)&pnv;
    float sx[4] = {0,0,0,0}, sn[4] = {0,0,0,0}, sd[4] = {0,0,0,0};
    #pragma unroll 4
    for (int t = 0; t < LSUB; ++t) {
        float4 xv = xp[(size_t)t * CG];
        float4 mv = mp[(size_t)t * CG];
        const float* xe = (const float*)&xv;
        const float* me = (const float*)&mv;
        #pragma unroll
        for (int j = 0; j < 4; ++j) {
            float nm = 1.0f - me[j];
            sx[j] += xe[j];
            sn[j] += nm;
            float n    = pn[j] + sn[j];
            float neff = (n == 0.0f) ? 1.0f : n;
            float mean = (px[j] + sx[j]) / neff;
            float d    = (xe[j] - mean) * nm;
            sd[j] += d * d;
        }
    }
    sumd2[o] = make_float4(sd[0], sd[1], sd[2], sd[3]);
}

__global__ __launch_bounds__(256) void k_finalize(
    const float* __restrict__ x, const float* __restrict__ mask,
    const float4* __restrict__ psumx, const float4* __restrict__ psumnm,
    const float4* __restrict__ psumd2, float* __restrict__ out)
{
    int gtid = blockIdx.x * 256 + threadIdx.x;
    int b, k, cg; decomp(gtid, b, k, cg);
    size_t base = ((size_t)b * T + (size_t)k * LSUB) * C;
    const float4* xp = reinterpret_cast<const float4*>(x + base) + cg;
    const float4* mp = reinterpret_cast<const float4*>(mask + base) + cg;
    float4* op = reinterpret_cast<float4*>(out + base) + cg;
    size_t o = ((size_t)b * NC + k) * CG + cg;
    float4 pxv = psumx[o];
    float4 pnv = psumnm[o];
    float4 pdv = psumd2[o];
    const float* px = (const float*)&pxv;
    const float* pn = (const float*)&pnv;
    const float* pd = (const float*)&pdv;
    float sx[4] = {0,0,0,0}, sn[4] = {0,0,0,0}, sd[4] = {0,0,0,0};
    #pragma unroll 4
    for (int t = 0; t < LSUB; ++t) {
        float4 xv = xp[(size_t)t * CG];
        float4 mv = mp[(size_t)t * CG];
        const float* xe = (const float*)&xv;
        const float* me = (const float*)&mv;
        float4 ov;
        float* oe = (float*)&ov;
        #pragma unroll
        for (int j = 0; j < 4; ++j) {
            float nm = 1.0f - me[j];
            sx[j] += xe[j];
            sn[j] += nm;
            float n    = pn[j] + sn[j];
            float neff = (n == 0.0f) ? 1.0f : n;
            float mean = (px[j] + sx[j]) / neff;
            float d    = (xe[j] - mean) * nm;
            sd[j] += d * d;
            float s = sqrtf((pd[j] + sd[j]) / neff);
            s = (s > STD_MIN) ? s : 1.0f;
            float v = (xe[j] - mean) / s;
            v = fminf(fmaxf(v, -MAX_VAL), MAX_VAL);
            oe[j] = v;
        }
        op[(size_t)t * CG] = ov;
    }
}

extern "C" void kernel_launch(void* const* d_in, const int* in_sizes, int n_in,
                              void* d_out, int out_size, void* d_ws, size_t ws_size,
                              hipStream_t stream) {
    const float* x    = (const float*)d_in[0];
    const float* mask = (const float*)d_in[1];
    float* out = (float*)d_out;

    // ws layout: 3 arrays of [B][NC][C] floats (2 MiB each)
    size_t arr_elems = (size_t)B * NC * C;
    float4* sumx  = (float4*)d_ws;
    float4* sumnm = (float4*)((float*)d_ws + arr_elems);
    float4* sumd2 = (float4*)((float*)d_ws + 2 * arr_elems);

    int main_threads = B * NC * CG;         // 131072
    int main_blocks  = main_threads / 256;  // 512
    int pfx_blocks   = (B * CG + 255) / 256; // 2

    k_chunk_sums<<<main_blocks, 256, 0, stream>>>(x, mask, sumx, sumnm);
    k_prefix_two<<<pfx_blocks, 256, 0, stream>>>(sumx, sumnm);
    k_dev2_sums<<<main_blocks, 256, 0, stream>>>(x, mask, sumx, sumnm, sumd2);
    k_prefix_one<<<pfx_blocks, 256, 0, stream>>>(sumd2);
    k_finalize<<<main_blocks, 256, 0, stream>>>(x, mask, sumx, sumnm, sumd2, out);
}

// Round 2
// 109.447 us; speedup vs baseline: 1.4368x; 1.4368x over previous
//
#include <hip/hip_runtime.h>
#include <math.h>

// CausalRevIN: B=16, T=8192, C=128, fp32 in/out.
// 5-pass chunked-scan decomposition (no inter-block sync):
//   P1: per-chunk sums of x and nm=1-mask
//   P2: PARALLEL exclusive prefix over chunks (x, nm)  [was serial: 48.5us -> ~4us]
//   P3: per-chunk dev^2 sums using prefix offsets
//   P4: PARALLEL exclusive prefix over chunks (dev^2)
//   P5: final normalize + clip
constexpr int B = 16;
constexpr int T = 8192;
constexpr int C = 128;
constexpr int LSUB = 32;           // t-rows per thread chunk
constexpr int NC = T / LSUB;       // 256 chunks along T (== blockDim of prefix kernels)
constexpr int CG = C / 4;          // 32 float4 channel-groups
constexpr float STD_MIN = 1e-5f;
constexpr float MAX_VAL = 100.0f;

__device__ inline void decomp(int gtid, int& b, int& k, int& cg) {
    cg = gtid & (CG - 1);
    k  = (gtid / CG) & (NC - 1);
    b  = gtid / (CG * NC);
}

__global__ __launch_bounds__(256) void k_chunk_sums(
    const float* __restrict__ x, const float* __restrict__ mask,
    float4* __restrict__ sumx, float4* __restrict__ sumnm)
{
    int gtid = blockIdx.x * 256 + threadIdx.x;
    int b, k, cg; decomp(gtid, b, k, cg);
    size_t base = ((size_t)b * T + (size_t)k * LSUB) * C;
    const float4* xp = reinterpret_cast<const float4*>(x + base) + cg;
    const float4* mp = reinterpret_cast<const float4*>(mask + base) + cg;
    float sx[4] = {0,0,0,0}, sn[4] = {0,0,0,0};
    #pragma unroll 8
    for (int t = 0; t < LSUB; ++t) {
        float4 xv = xp[(size_t)t * CG];
        float4 mv = mp[(size_t)t * CG];
        const float* xe = (const float*)&xv;
        const float* me = (const float*)&mv;
        #pragma unroll
        for (int j = 0; j < 4; ++j) {
            sx[j] += xe[j];
            sn[j] += 1.0f - me[j];
        }
    }
    size_t o = ((size_t)b * NC + k) * CG + cg;
    sumx[o]  = make_float4(sx[0], sx[1], sx[2], sx[3]);
    sumnm[o] = make_float4(sn[0], sn[1], sn[2], sn[3]);
}

// ---- parallel exclusive block scan over the NC dimension -------------------
// One block per (b, cg); thread k owns chunk k. Wave64 shuffle inclusive scan
// + LDS cross-wave combine; exact exclusive via shift-by-1.
template <int NCOMP>
__device__ inline void block_exscan(float* vals, int lane, int wave)
{
    float inc[NCOMP];
    #pragma unroll
    for (int j = 0; j < NCOMP; ++j) inc[j] = vals[j];
    #pragma unroll
    for (int d = 1; d < 64; d <<= 1) {
        #pragma unroll
        for (int j = 0; j < NCOMP; ++j) {
            float u = __shfl_up(inc[j], d, 64);
            if (lane >= d) inc[j] += u;
        }
    }
    __shared__ float wsum[4][NCOMP];
    if (lane == 63) {
        #pragma unroll
        for (int j = 0; j < NCOMP; ++j) wsum[wave][j] = inc[j];
    }
    __syncthreads();
    float off[NCOMP];
    #pragma unroll
    for (int j = 0; j < NCOMP; ++j) off[j] = 0.0f;
    for (int w = 0; w < wave; ++w) {
        #pragma unroll
        for (int j = 0; j < NCOMP; ++j) off[j] += wsum[w][j];
    }
    // exclusive within wave: shift inclusive down by one lane
    #pragma unroll
    for (int j = 0; j < NCOMP; ++j) {
        float e = __shfl_up(inc[j], 1, 64);
        vals[j] = off[j] + ((lane == 0) ? 0.0f : e);
    }
}

__global__ __launch_bounds__(256) void k_prefix_two_par(
    float4* __restrict__ a0, float4* __restrict__ a1)
{
    int blk = blockIdx.x;            // b*CG + cg, 512 blocks
    int cg = blk & (CG - 1);
    int b  = blk / CG;
    int k  = threadIdx.x;            // == chunk index, NC = 256
    int lane = k & 63, wave = k >> 6;
    size_t o = ((size_t)b * NC + k) * CG + cg;
    float4 v0 = a0[o];
    float4 v1 = a1[o];
    float vals[8] = {v0.x, v0.y, v0.z, v0.w, v1.x, v1.y, v1.z, v1.w};
    block_exscan<8>(vals, lane, wave);
    a0[o] = make_float4(vals[0], vals[1], vals[2], vals[3]);
    a1[o] = make_float4(vals[4], vals[5], vals[6], vals[7]);
}

__global__ __launch_bounds__(256) void k_prefix_one_par(float4* __restrict__ a0)
{
    int blk = blockIdx.x;
    int cg = blk & (CG - 1);
    int b  = blk / CG;
    int k  = threadIdx.x;
    int lane = k & 63, wave = k >> 6;
    size_t o = ((size_t)b * NC + k) * CG + cg;
    float4 v0 = a0[o];
    float vals[4] = {v0.x, v0.y, v0.z, v0.w};
    block_exscan<4>(vals, lane, wave);
    a0[o] = make_float4(vals[0], vals[1], vals[2], vals[3]);
}
// ---------------------------------------------------------------------------

__global__ __launch_bounds__(256) void k_dev2_sums(
    const float* __restrict__ x, const float* __restrict__ mask,
    const float4* __restrict__ psumx, const float4* __restrict__ psumnm,
    float4* __restrict__ sumd2)
{
    int gtid = blockIdx.x * 256 + threadIdx.x;
    int b, k, cg; decomp(gtid, b, k, cg);
    size_t base = ((size_t)b * T + (size_t)k * LSUB) * C;
    const float4* xp = reinterpret_cast<const float4*>(x + base) + cg;
    const float4* mp = reinterpret_cast<const float4*>(mask + base) + cg;
    size_t o = ((size_t)b * NC + k) * CG + cg;
    float4 pxv = psumx[o];
    float4 pnv = psumnm[o];
    const float* px = (const float*)&pxv;
    const float* pn = (const float*)&pnv;
    float sx[4] = {0,0,0,0}, sn[4] = {0,0,0,0}, sd[4] = {0,0,0,0};
    #pragma unroll 4
    for (int t = 0; t < LSUB; ++t) {
        float4 xv = xp[(size_t)t * CG];
        float4 mv = mp[(size_t)t * CG];
        const float* xe = (const float*)&xv;
        const float* me = (const float*)&mv;
        #pragma unroll
        for (int j = 0; j < 4; ++j) {
            float nm = 1.0f - me[j];
            sx[j] += xe[j];
            sn[j] += nm;
            float n    = pn[j] + sn[j];
            float neff = (n == 0.0f) ? 1.0f : n;
            float mean = (px[j] + sx[j]) / neff;
            float d    = (xe[j] - mean) * nm;
            sd[j] += d * d;
        }
    }
    sumd2[o] = make_float4(sd[0], sd[1], sd[2], sd[3]);
}

__global__ __launch_bounds__(256) void k_finalize(
    const float* __restrict__ x, const float* __restrict__ mask,
    const float4* __restrict__ psumx, const float4* __restrict__ psumnm,
    const float4* __restrict__ psumd2, float* __restrict__ out)
{
    int gtid = blockIdx.x * 256 + threadIdx.x;
    int b, k, cg; decomp(gtid, b, k, cg);
    size_t base = ((size_t)b * T + (size_t)k * LSUB) * C;
    const float4* xp = reinterpret_cast<const float4*>(x + base) + cg;
    const float4* mp = reinterpret_cast<const float4*>(mask + base) + cg;
    float4* op = reinterpret_cast<float4*>(out + base) + cg;
    size_t o = ((size_t)b * NC + k) * CG + cg;
    float4 pxv = psumx[o];
    float4 pnv = psumnm[o];
    float4 pdv = psumd2[o];
    const float* px = (const float*)&pxv;
    const float* pn = (const float*)&pnv;
    const float* pd = (const float*)&pdv;
    float sx[4] = {0,0,0,0}, sn[4] = {0,0,0,0}, sd[4] = {0,0,0,0};
    #pragma unroll 4
    for (int t = 0; t < LSUB; ++t) {
        float4 xv = xp[(size_t)t * CG];
        float4 mv = mp[(size_t)t * CG];
        const float* xe = (const float*)&xv;
        const float* me = (const float*)&mv;
        float4 ov;
        float* oe = (float*)&ov;
        #pragma unroll
        for (int j = 0; j < 4; ++j) {
            float nm = 1.0f - me[j];
            sx[j] += xe[j];
            sn[j] += nm;
            float n    = pn[j] + sn[j];
            float neff = (n == 0.0f) ? 1.0f : n;
            float mean = (px[j] + sx[j]) / neff;
            float d    = (xe[j] - mean) * nm;
            sd[j] += d * d;
            float s = sqrtf((pd[j] + sd[j]) / neff);
            s = (s > STD_MIN) ? s : 1.0f;
            float v = (xe[j] - mean) / s;
            v = fminf(fmaxf(v, -MAX_VAL), MAX_VAL);
            oe[j] = v;
        }
        op[(size_t)t * CG] = ov;
    }
}

extern "C" void kernel_launch(void* const* d_in, const int* in_sizes, int n_in,
                              void* d_out, int out_size, void* d_ws, size_t ws_size,
                              hipStream_t stream) {
    const float* x    = (const float*)d_in[0];
    const float* mask = (const float*)d_in[1];
    float* out = (float*)d_out;

    // ws layout: 3 arrays of [B][NC][C] floats (2 MiB each)
    size_t arr_elems = (size_t)B * NC * C;
    float4* sumx  = (float4*)d_ws;
    float4* sumnm = (float4*)((float*)d_ws + arr_elems);
    float4* sumd2 = (float4*)((float*)d_ws + 2 * arr_elems);

    int main_threads = B * NC * CG;         // 131072
    int main_blocks  = main_threads / 256;  // 512
    int scan_blocks  = B * CG;              // 512 (one per b,cg)

    k_chunk_sums<<<main_blocks, 256, 0, stream>>>(x, mask, sumx, sumnm);
    k_prefix_two_par<<<scan_blocks, 256, 0, stream>>>(sumx, sumnm);
    k_dev2_sums<<<main_blocks, 256, 0, stream>>>(x, mask, sumx, sumnm, sumd2);
    k_prefix_one_par<<<scan_blocks, 256, 0, stream>>>(sumd2);
    k_finalize<<<main_blocks, 256, 0, stream>>>(x, mask, sumx, sumnm, sumd2, out);
}